// Round 9
// baseline (275.302 us; speedup 1.0000x reference)
//
#include <hip/hip_runtime.h>
#include <math.h>

// ---- geometry ----
// Grid 50^3, coords shifted +1 -> occupy [1,50]. Dense key = (z*54+y)*64+x.
#define GY 54
#define NROWS (54*54*64)      // 186624 keys

// brick 8x4x4 = 128 output voxels per block; halo 10x6x6 = 360 rows
#define HX 10
#define HY 6
#define HXY 60
#define NH 360
#define NBX 7
#define NBY 13
#define NBRICK (7*13*13)      // 1183
#define SLAB 148              // ceil(1183/8)

#define LDH 36                // LDS row stride in bf16 for 32-ch rows (72B)

typedef __bf16  bf16x8 __attribute__((ext_vector_type(8)));
typedef float  f32x16 __attribute__((ext_vector_type(16)));

// ---- fused prep: maps + reverse keys + W -> Wt2 [2 ci-halves][27][cout][32cin] bf16 ----
__global__ void prep_kernel(const float* __restrict__ ipos, int n,
                            const float* __restrict__ opos, int m,
                            const float* __restrict__ vsp,
                            const float* __restrict__ W,
                            int* __restrict__ imap, int* __restrict__ ikey,
                            int* __restrict__ omap, int* __restrict__ okey,
                            __bf16* __restrict__ Wt2) {
    int i = blockIdx.x * 256 + threadIdx.x;
    float vs = vsp[0];
    if (i < n) {
        int x = (int)floorf(ipos[3*i+0] / vs) + 1;
        int y = (int)floorf(ipos[3*i+1] / vs) + 1;
        int z = (int)floorf(ipos[3*i+2] / vs) + 1;
        int key = (z * GY + y) * 64 + x;
        ikey[i] = key;
        imap[key] = i;
    } else if (i < n + m) {
        int j = i - n;
        int x = (int)floorf(opos[3*j+0] / vs) + 1;
        int y = (int)floorf(opos[3*j+1] / vs) + 1;
        int z = (int)floorf(opos[3*j+2] / vs) + 1;
        int key = (z * GY + y) * 64 + x;
        okey[j] = key;
        omap[key] = j;
    } else if (i < n + m + 27*64*64) {
        int k  = i - n - m;
        int t  = k >> 12;
        int r  = k & 4095;
        int ci = r >> 6;
        int co = r & 63;
        int h   = ci >> 5;
        int cil = ci & 31;
        Wt2[(((h * 27 + t) << 6) + co) * 32 + cil] = (__bf16)W[k];
    }
}

__global__ __launch_bounds__(256, 4) void conv_kernel(
    const float* __restrict__ feats,    // [N,64] fp32
    const __bf16* __restrict__ Wt2,     // [2][27][64cout][32cin]
    const float* __restrict__ bias,     // [64]
    const int*   __restrict__ imap,
    const int*   __restrict__ ikey,
    const int*   __restrict__ omap,
    const int*   __restrict__ okey,
    float*       __restrict__ out,      // [M,64]
    int N, int M)
{
    __shared__ __align__(16) __bf16 halo[NH * LDH];    // 25920 B
    __shared__ __align__(16) __bf16 Bld[2][64 * LDH];  //  9216 B
    __shared__ int ridx[NH];                           //  1440 B
    __shared__ int obuf[128];                          //   512 B
    // total ~37 KB -> 4 blocks/CU

    const int tid = threadIdx.x;

    // XCD slab swizzle
    int q = (blockIdx.x & 7) * SLAB + (blockIdx.x >> 3);
    if (q >= NBRICK) return;   // block-uniform exit before any barrier
    const int bx = q % NBX;
    int rem = q / NBX;
    const int by = rem % NBY;
    const int bz = rem / NBY;

    // ---- resolve halo row indices (validated) + output rows ----
    #pragma unroll
    for (int it = 0; it < 2; ++it) {
        int r = it * 256 + tid;
        if (r < NH) {
            int xs = r % HX;
            int t2 = r / HX;
            int ys = t2 % HY;
            int zs = t2 / HY;
            int key = ((bz*4 + zs) * GY + (by*4 + ys)) * 64 + (bx*8 + xs);
            int idx = imap[key];
            int c = min(max(idx, 0), N - 1);
            ridx[r] = (idx >= 0 && idx < N && ikey[c] == key) ? idx : -1;
        }
    }
    if (tid < 128) {
        int x = tid & 7, y = (tid >> 3) & 3, z = tid >> 5;
        int key = ((bz*4 + z + 1) * GY + (by*4 + y + 1)) * 64 + (bx*8 + x + 1);
        int o = omap[key];
        int c = min(max(o, 0), M - 1);
        obuf[tid] = (o >= 0 && o < M && okey[c] == key) ? o : -1;
    }

    // compute roles: wave = z-slice (1 m-tile of 32 pts), both n-tiles
    const int wave  = tid >> 6;
    const int lane  = tid & 63;
    const int lrow  = lane & 31;
    const int halfk = lane >> 5;
    const int xv = lrow & 7, yv = (lrow >> 3) & 3;
    const __bf16* Abase = halo + ((wave + 1) * HXY + (yv + 1) * HX + (xv + 1)) * LDH
                               + halfk * 8;
    const int Bb0 = lrow * LDH + halfk * 8;
    const int Bb1 = Bb0 + 32 * LDH;

    // B staging role: 256 float4 tasks (64 rows x 4 chunks of 16B)
    const int wr = tid >> 2;
    const int wc = tid & 3;

    f32x16 acc0, acc1;
    #pragma unroll
    for (int i = 0; i < 16; ++i) { acc0[i] = 0.f; acc1[i] = 0.f; }

    __syncthreads();   // ridx + obuf visible

    for (int h = 0; h < 2; ++h) {
        // ---- halo fill: 32 channels [32h..32h+32) of each of 360 rows ----
        // (h=1 overwrite is safe: last tap's end barrier precedes this)
        #pragma unroll
        for (int it = 0; it < 6; ++it) {
            int task = it * 256 + tid;
            if (task < NH * 4) {
                int r = task >> 2, c = task & 3;
                int idx = ridx[r];
                bf16x8 v;
                if (idx >= 0) {
                    const float4* s = (const float4*)(feats + (size_t)idx * 64 + h * 32 + c * 8);
                    float4 f0 = s[0], f1 = s[1];
                    v[0]=(__bf16)f0.x; v[1]=(__bf16)f0.y; v[2]=(__bf16)f0.z; v[3]=(__bf16)f0.w;
                    v[4]=(__bf16)f1.x; v[5]=(__bf16)f1.y; v[6]=(__bf16)f1.z; v[7]=(__bf16)f1.w;
                } else {
                    #pragma unroll
                    for (int j = 0; j < 8; ++j) v[j] = (__bf16)0.f;
                }
                *(bf16x8*)(halo + r * LDH + c * 8) = v;
            }
        }

        // ---- B: stage tap 0 of this half, prefetch tap 1 into regs ----
        const __bf16* Wh = Wt2 + h * 27 * 2048;
        float4 wreg = *(const float4*)(Wh + wr * 32 + wc * 8);
        *(float4*)(&Bld[0][wr * LDH + wc * 8]) = wreg;
        wreg = *(const float4*)(Wh + 2048 + wr * 32 + wc * 8);

        __syncthreads();   // halo + Bld[0] visible

        // A register pipeline: tap 0
        bf16x8 acur0, acur1;
        {
            const __bf16* Ab = Abase + (-HXY - HX - 1) * LDH;   // d=(-1,-1,-1)
            acur0 = *(const bf16x8*)(Ab);
            acur1 = *(const bf16x8*)(Ab + 16);
        }

        #pragma unroll
        for (int t = 0; t < 27; ++t) {
            // stage B(t+1) regs -> alternate buffer
            if (t < 26) {
                *(float4*)(&Bld[(t + 1) & 1][wr * LDH + wc * 8]) = wreg;
            }
            // issue W global load for tap t+2
            if (t < 25) {
                wreg = *(const float4*)(Wh + (t + 2) * 2048 + wr * 32 + wc * 8);
            }

            const __bf16* Bbuf = &Bld[t & 1][0];
            bf16x8 b00 = *(const bf16x8*)(Bbuf + Bb0);        // n-tile 0, kc 0
            bf16x8 b01 = *(const bf16x8*)(Bbuf + Bb0 + 16);   // n-tile 0, kc 1
            bf16x8 b10 = *(const bf16x8*)(Bbuf + Bb1);        // n-tile 1, kc 0
            bf16x8 b11 = *(const bf16x8*)(Bbuf + Bb1 + 16);   // n-tile 1, kc 1

            // prefetch A(t+1) (halo static, no barrier dependency)
            bf16x8 an0, an1;
            if (t < 26) {
                const int tn = t + 1;
                const int dx = tn % 3 - 1;
                const int dy = (tn / 3) % 3 - 1;
                const int dz = tn / 9 - 1;
                const __bf16* An = Abase + (dz * HXY + dy * HX + dx) * LDH;
                an0 = *(const bf16x8*)(An);
                an1 = *(const bf16x8*)(An + 16);
            }

            acc0 = __builtin_amdgcn_mfma_f32_32x32x16_bf16(acur0, b00, acc0, 0, 0, 0);
            acc1 = __builtin_amdgcn_mfma_f32_32x32x16_bf16(acur0, b10, acc1, 0, 0, 0);
            acc0 = __builtin_amdgcn_mfma_f32_32x32x16_bf16(acur1, b01, acc0, 0, 0, 0);
            acc1 = __builtin_amdgcn_mfma_f32_32x32x16_bf16(acur1, b11, acc1, 0, 0, 0);

            if (t < 26) { acur0 = an0; acur1 = an1; }
            __syncthreads();   // B-dbuf publish / read separation
        }
    }

    // ---- epilogue: C/D layout col=lane&31, row=(reg&3)+8*(reg>>2)+4*(lane>>5) ----
    const int col0 = lrow, col1 = 32 + lrow;
    const float bv0 = bias[col0], bv1 = bias[col1];
    #pragma unroll
    for (int r = 0; r < 16; ++r) {
        int mrow = (r & 3) + 8 * (r >> 2) + 4 * halfk;
        int orow = obuf[wave * 32 + mrow];
        if (orow >= 0) {
            out[(size_t)orow * 64 + col0] = acc0[r] + bv0;
            out[(size_t)orow * 64 + col1] = acc1[r] + bv1;
        }
    }
}

extern "C" void kernel_launch(void* const* d_in, const int* in_sizes, int n_in,
                              void* d_out, int out_size, void* d_ws, size_t ws_size,
                              hipStream_t stream) {
    const float* feats = (const float*)d_in[0];
    const float* ipos  = (const float*)d_in[1];
    const float* opos  = (const float*)d_in[2];
    const float* vsp   = (const float*)d_in[3];
    const float* W     = (const float*)d_in[4];
    const float* bias  = (const float*)d_in[5];

    int N = in_sizes[0] / 64;
    int M = out_size / 64;

    // workspace: imap | omap | ikey | okey | Wt2   (no clearing required)
    int*    imap = (int*)d_ws;
    int*    omap = imap + NROWS;
    int*    ikey = omap + NROWS;
    int*    okey = ikey + N;
    __bf16* Wt2  = (__bf16*)(okey + M);

    int total = N + M + 27*64*64;
    prep_kernel<<<(total + 255) / 256, 256, 0, stream>>>(ipos, N, opos, M, vsp, W,
                                                         imap, ikey, omap, okey, Wt2);
    conv_kernel<<<8 * SLAB, 256, 0, stream>>>(feats, Wt2, bias, imap, ikey, omap, okey,
                                              (float*)d_out, N, M);
}

// Round 10
// 149.386 us; speedup vs baseline: 1.8429x; 1.8429x over previous
//
#include <hip/hip_runtime.h>
#include <math.h>

// ---- geometry ----
// Grid 50^3, coords shifted +1 -> occupy [1,50]. Dense key = (z*GY+y)*64+x.
// 8-deep z bricks probe z up to 57 -> z-dim 58.
#define GY 54
#define ZD 58
#define NROWS (ZD*GY*64)      // 200448 keys

// brick 8x4x8 = 256 output voxels per block; halo 10x6x10 = 600 rows
#define HX 10
#define HY 6
#define HXY 60                // rows per z-slice
#define NH 600
#define NBX 7                 // ceil(50/8)
#define NBY 13                // ceil(50/4)
#define NBZ 7                 // ceil(50/8)
#define NBRICK (NBX*NBY*NBZ)  // 637
#define SLAB 80               // ceil(637/8)

#define LDH 40                // LDS row stride in bf16: 80 B = 5*16B (16B-aligned, odd -> conflict-free)

typedef __bf16  bf16x8 __attribute__((ext_vector_type(8)));
typedef float  f32x16 __attribute__((ext_vector_type(16)));

// ---- fused prep: maps + reverse keys + W -> Wt2 [2 ci-halves][27][64cout][32cin] ----
__global__ void prep_kernel(const float* __restrict__ ipos, int n,
                            const float* __restrict__ opos, int m,
                            const float* __restrict__ vsp,
                            const float* __restrict__ W,
                            int* __restrict__ imap, int* __restrict__ ikey,
                            int* __restrict__ omap, int* __restrict__ okey,
                            __bf16* __restrict__ Wt2) {
    int i = blockIdx.x * 256 + threadIdx.x;
    float vs = vsp[0];
    if (i < n) {
        int x = (int)floorf(ipos[3*i+0] / vs) + 1;
        int y = (int)floorf(ipos[3*i+1] / vs) + 1;
        int z = (int)floorf(ipos[3*i+2] / vs) + 1;
        int key = (z * GY + y) * 64 + x;
        ikey[i] = key;
        imap[key] = i;
    } else if (i < n + m) {
        int j = i - n;
        int x = (int)floorf(opos[3*j+0] / vs) + 1;
        int y = (int)floorf(opos[3*j+1] / vs) + 1;
        int z = (int)floorf(opos[3*j+2] / vs) + 1;
        int key = (z * GY + y) * 64 + x;
        okey[j] = key;
        omap[key] = j;
    } else if (i < n + m + 27*64*64) {
        int k  = i - n - m;
        int t  = k >> 12;
        int r  = k & 4095;
        int ci = r >> 6;
        int co = r & 63;
        int h   = ci >> 5;
        int cil = ci & 31;
        Wt2[(((h * 27 + t) << 6) + co) * 32 + cil] = (__bf16)W[k];
    }
}

__global__ __launch_bounds__(256, 2) void conv_kernel(
    const float* __restrict__ feats,    // [N,64] fp32
    const __bf16* __restrict__ Wt2,     // [2][27][64cout][32cin]
    const float* __restrict__ bias,     // [64]
    const int*   __restrict__ imap,
    const int*   __restrict__ ikey,
    const int*   __restrict__ omap,
    const int*   __restrict__ okey,
    float*       __restrict__ out,      // [M,64]
    int N, int M)
{
    __shared__ __align__(16) __bf16 halo[NH * LDH];    // 48000 B
    __shared__ __align__(16) __bf16 Bld[2][64 * LDH];  // 10240 B
    __shared__ int ridx[NH];                           //  2400 B
    __shared__ int obuf[256];                          //  1024 B
    // total ~61.7 KB -> 2 blocks/CU

    const int tid = threadIdx.x;

    // XCD slab swizzle
    int q = (blockIdx.x & 7) * SLAB + (blockIdx.x >> 3);
    if (q >= NBRICK) return;   // block-uniform exit before any barrier
    const int bx = q % NBX;
    int rem = q / NBX;
    const int by = rem % NBY;
    const int bz = rem / NBY;

    // ---- resolve halo row indices (validated) + output rows ----
    #pragma unroll
    for (int it = 0; it < 3; ++it) {
        int r = it * 256 + tid;
        if (r < NH) {
            int xs = r % HX;
            int t2 = r / HX;
            int ys = t2 % HY;
            int zs = t2 / HY;
            int key = ((bz*8 + zs) * GY + (by*4 + ys)) * 64 + (bx*8 + xs);
            int idx = imap[key];
            int c = min(max(idx, 0), N - 1);
            ridx[r] = (idx >= 0 && idx < N && ikey[c] == key) ? idx : -1;
        }
    }
    {
        int x = tid & 7, y = (tid >> 3) & 3, z = tid >> 5;
        int key = ((bz*8 + z + 1) * GY + (by*4 + y + 1)) * 64 + (bx*8 + x + 1);
        int o = omap[key];
        int c = min(max(o, 0), M - 1);
        obuf[tid] = (o >= 0 && o < M && okey[c] == key) ? o : -1;
    }

    // compute roles: wave owns z-slices {2w, 2w+1} (2 m-tiles) x both n-tiles
    const int wave  = tid >> 6;
    const int lane  = tid & 63;
    const int lrow  = lane & 31;
    const int halfk = lane >> 5;
    const int xv = lrow & 7, yv = (lrow >> 3) & 3;
    const __bf16* Abase0 = halo + ((2*wave + 1) * HXY + (yv + 1) * HX + (xv + 1)) * LDH
                                + halfk * 8;
    const int Bb0 = lrow * LDH + halfk * 8;            // n-tile 0
    const int Bb1 = Bb0 + 32 * LDH;                    // n-tile 1

    // B staging role: 256 float4 tasks (64 rows x 4 chunks of 16B)
    const int wr = tid >> 2;
    const int wc = tid & 3;

    f32x16 acc00, acc01, acc10, acc11;
    #pragma unroll
    for (int i = 0; i < 16; ++i) { acc00[i]=0.f; acc01[i]=0.f; acc10[i]=0.f; acc11[i]=0.f; }

    __syncthreads();   // ridx + obuf visible

    for (int h = 0; h < 2; ++h) {
        // ---- halo fill: channels [32h, 32h+32) of each of 600 rows ----
        // (h=1 overwrite safe: previous t-loop ends with a barrier)
        #pragma unroll
        for (int it = 0; it < 10; ++it) {
            int task = it * 256 + tid;
            if (task < NH * 4) {
                int r = task >> 2, c = task & 3;
                int idx = ridx[r];
                bf16x8 v;
                if (idx >= 0) {
                    const float4* s = (const float4*)(feats + (size_t)idx * 64 + h * 32 + c * 8);
                    float4 f0 = s[0], f1 = s[1];
                    v[0]=(__bf16)f0.x; v[1]=(__bf16)f0.y; v[2]=(__bf16)f0.z; v[3]=(__bf16)f0.w;
                    v[4]=(__bf16)f1.x; v[5]=(__bf16)f1.y; v[6]=(__bf16)f1.z; v[7]=(__bf16)f1.w;
                } else {
                    #pragma unroll
                    for (int j = 0; j < 8; ++j) v[j] = (__bf16)0.f;
                }
                *(bf16x8*)(halo + r * LDH + c * 8) = v;
            }
        }

        // ---- B: stage tap 0 of this half into buf0, prefetch tap 1 ----
        const __bf16* Wh = Wt2 + h * 27 * 2048;
        float4 wreg = *(const float4*)(Wh + wr * 32 + wc * 8);
        *(float4*)(&Bld[0][wr * LDH + wc * 8]) = wreg;
        wreg = *(const float4*)(Wh + 2048 + wr * 32 + wc * 8);

        __syncthreads();   // halo + Bld[0] visible

        // A register pipeline: tap 0, both m-tiles, both kc chunks
        bf16x8 acur[4];    // [m*2 + kc]
        {
            const __bf16* a0 = Abase0 + (-HXY - HX - 1) * LDH;   // d=(-1,-1,-1)
            acur[0] = *(const bf16x8*)(a0);
            acur[1] = *(const bf16x8*)(a0 + 16);
            acur[2] = *(const bf16x8*)(a0 + HXY * LDH);
            acur[3] = *(const bf16x8*)(a0 + HXY * LDH + 16);
        }

        #pragma unroll
        for (int t = 0; t < 27; ++t) {
            // stage B(t+1) regs -> alternate buffer
            if (t < 26) {
                *(float4*)(&Bld[(t + 1) & 1][wr * LDH + wc * 8]) = wreg;
            }
            // issue W global load for tap t+2
            if (t < 25) {
                wreg = *(const float4*)(Wh + (t + 2) * 2048 + wr * 32 + wc * 8);
            }

            const __bf16* Bbuf = &Bld[t & 1][0];
            bf16x8 b00 = *(const bf16x8*)(Bbuf + Bb0);        // n0, kc0
            bf16x8 b01 = *(const bf16x8*)(Bbuf + Bb0 + 16);   // n0, kc1
            bf16x8 b10 = *(const bf16x8*)(Bbuf + Bb1);        // n1, kc0
            bf16x8 b11 = *(const bf16x8*)(Bbuf + Bb1 + 16);   // n1, kc1

            // prefetch A(t+1) (halo static, no barrier dependency)
            bf16x8 an[4];
            if (t < 26) {
                const int tn = t + 1;
                const int dx = tn % 3 - 1;
                const int dy = (tn / 3) % 3 - 1;
                const int dz = tn / 9 - 1;
                const __bf16* An = Abase0 + (dz * HXY + dy * HX + dx) * LDH;
                an[0] = *(const bf16x8*)(An);
                an[1] = *(const bf16x8*)(An + 16);
                an[2] = *(const bf16x8*)(An + HXY * LDH);
                an[3] = *(const bf16x8*)(An + HXY * LDH + 16);
            }

            acc00 = __builtin_amdgcn_mfma_f32_32x32x16_bf16(acur[0], b00, acc00, 0, 0, 0);
            acc01 = __builtin_amdgcn_mfma_f32_32x32x16_bf16(acur[0], b10, acc01, 0, 0, 0);
            acc10 = __builtin_amdgcn_mfma_f32_32x32x16_bf16(acur[2], b00, acc10, 0, 0, 0);
            acc11 = __builtin_amdgcn_mfma_f32_32x32x16_bf16(acur[2], b10, acc11, 0, 0, 0);
            acc00 = __builtin_amdgcn_mfma_f32_32x32x16_bf16(acur[1], b01, acc00, 0, 0, 0);
            acc01 = __builtin_amdgcn_mfma_f32_32x32x16_bf16(acur[1], b11, acc01, 0, 0, 0);
            acc10 = __builtin_amdgcn_mfma_f32_32x32x16_bf16(acur[3], b01, acc10, 0, 0, 0);
            acc11 = __builtin_amdgcn_mfma_f32_32x32x16_bf16(acur[3], b11, acc11, 0, 0, 0);

            if (t < 26) {
                #pragma unroll
                for (int j = 0; j < 4; ++j) acur[j] = an[j];
            }
            __syncthreads();   // B-dbuf publish / read separation
        }
    }

    // ---- epilogue: C/D layout col=lane&31, row=(reg&3)+8*(reg>>2)+4*(lane>>5) ----
    const int col0 = lrow, col1 = 32 + lrow;
    const float bv0 = bias[col0], bv1 = bias[col1];
    #pragma unroll
    for (int r = 0; r < 16; ++r) {
        int mrow = (r & 3) + 8 * (r >> 2) + 4 * halfk;
        int o0 = obuf[(2*wave)     * 32 + mrow];
        int o1 = obuf[(2*wave + 1) * 32 + mrow];
        if (o0 >= 0) {
            out[(size_t)o0 * 64 + col0] = acc00[r] + bv0;
            out[(size_t)o0 * 64 + col1] = acc01[r] + bv1;
        }
        if (o1 >= 0) {
            out[(size_t)o1 * 64 + col0] = acc10[r] + bv0;
            out[(size_t)o1 * 64 + col1] = acc11[r] + bv1;
        }
    }
}

extern "C" void kernel_launch(void* const* d_in, const int* in_sizes, int n_in,
                              void* d_out, int out_size, void* d_ws, size_t ws_size,
                              hipStream_t stream) {
    const float* feats = (const float*)d_in[0];
    const float* ipos  = (const float*)d_in[1];
    const float* opos  = (const float*)d_in[2];
    const float* vsp   = (const float*)d_in[3];
    const float* W     = (const float*)d_in[4];
    const float* bias  = (const float*)d_in[5];

    int N = in_sizes[0] / 64;
    int M = out_size / 64;

    // workspace: imap | omap | ikey | okey | Wt2   (no clearing required)
    int*    imap = (int*)d_ws;
    int*    omap = imap + NROWS;
    int*    ikey = omap + NROWS;
    int*    okey = ikey + N;
    __bf16* Wt2  = (__bf16*)(okey + M);

    int total = N + M + 27*64*64;
    prep_kernel<<<(total + 255) / 256, 256, 0, stream>>>(ipos, N, opos, M, vsp, W,
                                                         imap, ikey, omap, okey, Wt2);
    conv_kernel<<<8 * SLAB, 256, 0, stream>>>(feats, Wt2, bias, imap, ikey, omap, okey,
                                              (float*)d_out, N, M);
}

// Round 11
// 144.673 us; speedup vs baseline: 1.9029x; 1.0326x over previous
//
#include <hip/hip_runtime.h>
#include <math.h>

// ---- geometry ----
// Grid 50^3, coords shifted +1 -> occupy [1,50]. Dense key = (z*GY+y)*64+x.
// 8-deep z bricks probe z up to 57 -> z-dim 58.
#define GY 54
#define ZD 58
#define NROWS (ZD*GY*64)      // 200448 keys

// brick 8x4x8 = 256 output voxels per block; halo 10x6x10 = 600 rows
#define HX 10
#define HY 6
#define HXY 60                // halo rows per z-slice
#define NH 600
#define NBX 7
#define NBY 13
#define NBZ 7
#define NBRICK (NBX*NBY*NBZ)  // 637
#define SLAB 80               // ceil(637/8)

typedef __bf16  bf16x8 __attribute__((ext_vector_type(8)));
typedef float  f32x16 __attribute__((ext_vector_type(16)));

// ---- fused prep: maps + reverse keys + W -> Wt4 [4 ci-quarters][27][64cout][16cin] ----
__global__ void prep_kernel(const float* __restrict__ ipos, int n,
                            const float* __restrict__ opos, int m,
                            const float* __restrict__ vsp,
                            const float* __restrict__ W,
                            int* __restrict__ imap, int* __restrict__ ikey,
                            int* __restrict__ omap, int* __restrict__ okey,
                            __bf16* __restrict__ Wt4) {
    int i = blockIdx.x * 256 + threadIdx.x;
    float vs = vsp[0];
    if (i < n) {
        int x = (int)floorf(ipos[3*i+0] / vs) + 1;
        int y = (int)floorf(ipos[3*i+1] / vs) + 1;
        int z = (int)floorf(ipos[3*i+2] / vs) + 1;
        int key = (z * GY + y) * 64 + x;
        ikey[i] = key;
        imap[key] = i;
    } else if (i < n + m) {
        int j = i - n;
        int x = (int)floorf(opos[3*j+0] / vs) + 1;
        int y = (int)floorf(opos[3*j+1] / vs) + 1;
        int z = (int)floorf(opos[3*j+2] / vs) + 1;
        int key = (z * GY + y) * 64 + x;
        okey[j] = key;
        omap[key] = j;
    } else if (i < n + m + 27*64*64) {
        int k  = i - n - m;
        int t  = k >> 12;
        int r  = k & 4095;
        int ci = r >> 6;
        int co = r & 63;
        int p   = ci >> 4;
        int cil = ci & 15;
        Wt4[(((p * 27 + t) << 6) + co) * 16 + cil] = (__bf16)W[k];
    }
}

__global__ __launch_bounds__(256, 2) void conv_kernel(
    const float* __restrict__ feats,    // [N,64] fp32
    const __bf16* __restrict__ Wt4,     // [4][27][64cout][16cin]
    const float* __restrict__ bias,     // [64]
    const int*   __restrict__ imap,
    const int*   __restrict__ ikey,
    const int*   __restrict__ omap,
    const int*   __restrict__ okey,
    float*       __restrict__ out,      // [M,64]
    int N, int M)
{
    __shared__ __align__(16) __bf16 halo[NH * 16];     // 19200 B  (row = 16 cin, 32B)
    __shared__ __align__(16) __bf16 Bq[27 * 64 * 16];  // 55296 B  (all taps, quarter-K)
    __shared__ int ridx[NH];                           //  2400 B
    __shared__ int obuf[256];                          //  1024 B
    // total ~77.9 KB -> 2 blocks/CU

    const int tid = threadIdx.x;

    // XCD slab swizzle
    int q = (blockIdx.x & 7) * SLAB + (blockIdx.x >> 3);
    if (q >= NBRICK) return;   // block-uniform exit before any barrier
    const int bx = q % NBX;
    int rem = q / NBX;
    const int by = rem % NBY;
    const int bz = rem / NBY;

    // ---- resolve halo row indices (validated) + output rows ----
    #pragma unroll
    for (int it = 0; it < 3; ++it) {
        int r = it * 256 + tid;
        if (r < NH) {
            int xs = r % HX;
            int t2 = r / HX;
            int ys = t2 % HY;
            int zs = t2 / HY;
            int key = ((bz*8 + zs) * GY + (by*4 + ys)) * 64 + (bx*8 + xs);
            int idx = imap[key];
            int c = min(max(idx, 0), N - 1);
            ridx[r] = (idx >= 0 && idx < N && ikey[c] == key) ? idx : -1;
        }
    }
    {
        int x = tid & 7, y = (tid >> 3) & 3, z = tid >> 5;
        int key = ((bz*8 + z + 1) * GY + (by*4 + y + 1)) * 64 + (bx*8 + x + 1);
        int o = omap[key];
        int c = min(max(o, 0), M - 1);
        obuf[tid] = (o >= 0 && o < M && okey[c] == key) ? o : -1;
    }

    // compute roles: wave owns z-slices {2w, 2w+1} (2 m-tiles) x both n-tiles
    const int wave  = tid >> 6;
    const int lane  = tid & 63;
    const int lrow  = lane & 31;
    const int halfk = lane >> 5;
    const int xv = lrow & 7, yv = (lrow >> 3) & 3;
    // A row index (halo row units) for m-tile 0 of this wave, before tap offset
    const int arow0 = (2*wave + 1) * HXY + (yv + 1) * HX + (xv + 1);
    const __bf16* Ab0 = halo + arow0 * 16 + halfk * 8;      // m-tile 0
    const __bf16* Ab1 = Ab0 + HXY * 16;                     // m-tile 1 (z+1)
    const __bf16* Bb0 = Bq + lrow * 16 + halfk * 8;         // n-tile 0 (tap adds t*1024)
    const __bf16* Bb1 = Bb0 + 32 * 16;                      // n-tile 1

    f32x16 acc00, acc01, acc10, acc11;
    #pragma unroll
    for (int i = 0; i < 16; ++i) { acc00[i]=0.f; acc01[i]=0.f; acc10[i]=0.f; acc11[i]=0.f; }

    __syncthreads();   // ridx + obuf visible

    #pragma unroll 1
    for (int p = 0; p < 4; ++p) {
        if (p) __syncthreads();   // previous pass's readers done before overwrite

        // ---- fill halo quarter: 600 rows x 16 cin (fp32 -> bf16) ----
        #pragma unroll
        for (int it = 0; it < 5; ++it) {
            int task = it * 256 + tid;
            if (task < NH * 2) {
                int r = task >> 1, hf = task & 1;   // hf: 8-channel half of the quarter
                int idx = ridx[r];
                bf16x8 v;
                if (idx >= 0) {
                    const float4* s = (const float4*)(feats + (size_t)idx * 64 + p * 16 + hf * 8);
                    float4 f0 = s[0], f1 = s[1];
                    v[0]=(__bf16)f0.x; v[1]=(__bf16)f0.y; v[2]=(__bf16)f0.z; v[3]=(__bf16)f0.w;
                    v[4]=(__bf16)f1.x; v[5]=(__bf16)f1.y; v[6]=(__bf16)f1.z; v[7]=(__bf16)f1.w;
                } else {
                    #pragma unroll
                    for (int j = 0; j < 8; ++j) v[j] = (__bf16)0.f;
                }
                *(bf16x8*)(halo + r * 16 + hf * 8) = v;
            }
        }

        // ---- fill B: all 27 taps' quarter (bf16 copy, coalesced) ----
        {
            const __bf16* Wp = Wt4 + (size_t)p * 27648;
            #pragma unroll
            for (int it = 0; it < 14; ++it) {
                int task = it * 256 + tid;           // 3456 bf16x8 chunks
                if (task < 3456) {
                    *(bf16x8*)(Bq + task * 8) = *(const bf16x8*)(Wp + task * 8);
                }
            }
        }

        __syncthreads();   // halo + Bq visible (drains the bulk fill ONCE)

        // ---- 27 taps: pure ds_read + MFMA, zero barriers, zero VMEM ----
        #pragma unroll
        for (int t = 0; t < 27; ++t) {
            const int dx = t % 3 - 1;
            const int dy = (t / 3) % 3 - 1;
            const int dz = t / 9 - 1;
            const int doff = (dz * HXY + dy * HX + dx) * 16;

            bf16x8 a0 = *(const bf16x8*)(Ab0 + doff);
            bf16x8 a1 = *(const bf16x8*)(Ab1 + doff);
            bf16x8 b0 = *(const bf16x8*)(Bb0 + t * 1024);
            bf16x8 b1 = *(const bf16x8*)(Bb1 + t * 1024);

            acc00 = __builtin_amdgcn_mfma_f32_32x32x16_bf16(a0, b0, acc00, 0, 0, 0);
            acc01 = __builtin_amdgcn_mfma_f32_32x32x16_bf16(a0, b1, acc01, 0, 0, 0);
            acc10 = __builtin_amdgcn_mfma_f32_32x32x16_bf16(a1, b0, acc10, 0, 0, 0);
            acc11 = __builtin_amdgcn_mfma_f32_32x32x16_bf16(a1, b1, acc11, 0, 0, 0);
        }
    }

    // ---- epilogue: C/D layout col=lane&31, row=(reg&3)+8*(reg>>2)+4*(lane>>5) ----
    const int col0 = lrow, col1 = 32 + lrow;
    const float bv0 = bias[col0], bv1 = bias[col1];
    #pragma unroll
    for (int r = 0; r < 16; ++r) {
        int mrow = (r & 3) + 8 * (r >> 2) + 4 * halfk;
        int o0 = obuf[(2*wave)     * 32 + mrow];
        int o1 = obuf[(2*wave + 1) * 32 + mrow];
        if (o0 >= 0) {
            out[(size_t)o0 * 64 + col0] = acc00[r] + bv0;
            out[(size_t)o0 * 64 + col1] = acc01[r] + bv1;
        }
        if (o1 >= 0) {
            out[(size_t)o1 * 64 + col0] = acc10[r] + bv0;
            out[(size_t)o1 * 64 + col1] = acc11[r] + bv1;
        }
    }
}

extern "C" void kernel_launch(void* const* d_in, const int* in_sizes, int n_in,
                              void* d_out, int out_size, void* d_ws, size_t ws_size,
                              hipStream_t stream) {
    const float* feats = (const float*)d_in[0];
    const float* ipos  = (const float*)d_in[1];
    const float* opos  = (const float*)d_in[2];
    const float* vsp   = (const float*)d_in[3];
    const float* W     = (const float*)d_in[4];
    const float* bias  = (const float*)d_in[5];

    int N = in_sizes[0] / 64;
    int M = out_size / 64;

    // workspace: imap | omap | ikey | okey | Wt4   (no clearing required)
    int*    imap = (int*)d_ws;
    int*    omap = imap + NROWS;
    int*    ikey = omap + NROWS;
    int*    okey = ikey + N;
    __bf16* Wt4  = (__bf16*)(okey + M);

    int total = N + M + 27*64*64;
    prep_kernel<<<(total + 255) / 256, 256, 0, stream>>>(ipos, N, opos, M, vsp, W,
                                                         imap, ikey, omap, okey, Wt4);
    conv_kernel<<<8 * SLAB, 256, 0, stream>>>(feats, Wt4, bias, imap, ikey, omap, okey,
                                              (float*)d_out, N, M);
}